// Round 7
// baseline (361.140 us; speedup 1.0000x reference)
//
#include <hip/hip_runtime.h>
#include <hip/hip_bf16.h>

#define NN 10000
#define NE 100000

typedef __attribute__((ext_vector_type(8))) short short8v;
typedef __attribute__((ext_vector_type(4))) float float4v;

__device__ __forceinline__ unsigned int enc_f(float f) {
  unsigned int u = __float_as_uint(f);
  return (u & 0x80000000u) ? ~u : (u | 0x80000000u);
}
__device__ __forceinline__ float dec_f(unsigned int u) {
  return __uint_as_float((u & 0x80000000u) ? (u & 0x7fffffffu) : ~u);
}
__device__ __forceinline__ float silu_f(float x) {
  return x / (1.0f + __expf(-x));
}
// fp32 -> bf16 hi/lo split: x ~= hi + lo with ~2^-16 relative error.
__device__ __forceinline__ void f32_hilo(float x, short& h, short& l) {
  __hip_bfloat16 bh = __float2bfloat16(x);
  float r = x - __bfloat162float(bh);
  __hip_bfloat16 bl = __float2bfloat16(r);
  h = __builtin_bit_cast(short, bh);
  l = __builtin_bit_cast(short, bl);
}
#define MFMA16(a, b, c) __builtin_amdgcn_mfma_f32_16x16x32_bf16(a, b, c, 0, 0, 0)

// ---------------- prep: Q + MFMA weight fragment packs.
// Pack layout per GEMM: idx = ((nt*KF + kf)*64 + lane)*8 + j
//   holds W[k][n] with k = kf*32 + 8*(lane>>4) + j, n = nt*16 + (lane&15).
// A and B use the SAME k bijection -> result invariant to the HW's actual k map.
// Wp4 packs W_msg TRANSPOSED: B[k=m][n=c2] = W_msg[c2*128 + m]  (t = u @ W_msg^T).
__global__ void prep_kernel(const float* __restrict__ W_msg, const float* __restrict__ W_val,
                            const float* __restrict__ W_out, const float* __restrict__ W_rbf,
                            const float* __restrict__ W_gate,
                            float* __restrict__ Q,
                            short* __restrict__ Wp1h, short* __restrict__ Wp1l,
                            short* __restrict__ Wp2h, short* __restrict__ Wp2l,
                            short* __restrict__ Wp3h, short* __restrict__ Wp3l,
                            short* __restrict__ Wp4h, short* __restrict__ Wp4l) {
  int i = blockIdx.x * blockDim.x + threadIdx.x;  // grid = 192*256 = 49152
  if (i < 1024) {
    int c = i >> 3, h = i & 7;
    float s = 0.0f;
#pragma unroll
    for (int dv = 0; dv < 16; ++dv)
      s += W_val[c * 128 + h * 16 + dv] * W_out[h * 16 + dv];
    Q[c * 8 + h] = s;
  }
  const float* W; short* ph; short* pl; int KF, Nw, local; bool tr = false;
  if (i < 8192)       { W = W_rbf;  ph = Wp1h; pl = Wp1l; KF = 4; Nw = 64;  local = i; }
  else if (i < 16384) { W = W_gate; ph = Wp2h; pl = Wp2l; KF = 2; Nw = 128; local = i - 8192; }
  else if (i < 32768) { W = W_msg;  ph = Wp3h; pl = Wp3l; KF = 4; Nw = 128; local = i - 16384; }
  else                { W = W_msg;  ph = Wp4h; pl = Wp4l; KF = 4; Nw = 128; local = i - 32768; tr = true; }
  int tile = local >> 9;           // nt*KF + kf
  int ln = (local >> 3) & 63;
  int j = local & 7;
  int nt = tile / KF, kf = tile % KF;
  int k = kf * 32 + 8 * (ln >> 4) + j;
  int n = nt * 16 + (ln & 15);
  float w = tr ? W[n * 128 + k] : W[k * Nw + n];
  short h, lo;
  f32_hilo(w, h, lo);
  ph[local] = h;
  pl[local] = lo;
}

// ---------------- G1: one wave per edge; writes x-concat as bf16 hi/lo
// (channel = lane), which IS the A-frag byte order P1 needs.
__global__ __launch_bounds__(256) void gather1_kernel(
    const float* __restrict__ nb, const int* __restrict__ ei,
    const float* __restrict__ wig, short* __restrict__ xch,
    short* __restrict__ xcl) {
  const int lane = threadIdx.x & 63;
  const int e = blockIdx.x * 4 + (threadIdx.x >> 6);  // NE % 4 == 0
  int se = ei[e], de = ei[NE + e];
  const float* __restrict__ pw = wig + (size_t)e * 81;
  const float* __restrict__ ps = nb + (size_t)se * 576 + lane;
  const float* __restrict__ pt = nb + (size_t)de * 576 + lane;
  float vs[9], vt[9], wj[9];
#pragma unroll
  for (int j = 0; j < 9; ++j) {
    vs[j] = ps[j * 64];
    vt[j] = pt[j * 64];
    wj[j] = pw[j];
  }
  float xs = 0.0f, xt = 0.0f;
#pragma unroll
  for (int j = 0; j < 9; ++j) { xs += wj[j] * vs[j]; xt += wj[j] * vt[j]; }
  short h, l;
  f32_hilo(xs, h, l);
  xch[(size_t)e * 128 + lane] = h;
  xcl[(size_t)e * 128 + lane] = l;
  f32_hilo(xt, h, l);
  xch[(size_t)e * 128 + 64 + lane] = h;
  xcl[(size_t)e * 128 + 64 + lane] = l;
}

// ---------------- P1 (MFMA, M=32): gate (bf16 ws), logits, segment-max.
// 2 m-tiles per wave: every B-frag load feeds 6 MFMAs; A3 frags are raw
// 16B loads from the pre-packed xch/xcl.
__global__ __launch_bounds__(256, 2) void pass1_kernel(
    const int* __restrict__ zn, const float* __restrict__ dist,
    const int* __restrict__ ei, const float* __restrict__ aemb,
    const float* __restrict__ alpha,
    const short* __restrict__ xch, const short* __restrict__ xcl,
    const short* __restrict__ Wp1h, const short* __restrict__ Wp1l,
    const short* __restrict__ Wp2h, const short* __restrict__ Wp2l,
    const short* __restrict__ Wp3h, const short* __restrict__ Wp3l,
    float* __restrict__ logits, unsigned int* __restrict__ m_enc,
    __hip_bfloat16* __restrict__ gate_ws) {
  __shared__ __attribute__((aligned(16))) float es_s[4][32][68];
  const int tid = threadIdx.x;
  const int lane = tid & 63;
  const int wid = tid >> 6;
  const int g = lane >> 4;
  const int col = lane & 15;
  const int e0 = (blockIdx.x * 4 + wid) * 32;

  // wave's 64 edge indices: lanes 0..31 = src(e=lane), 32..63 = dst(e=lane&31)
  int eb = e0 + (lane & 31); if (eb >= NE) eb = NE - 1;
  int idx_v = ei[(lane < 32 ? 0 : NE) + eb];

  // ---- A3 frags: raw 16B loads from packed xc (issued first) ----
  short8v a3h[2][4], a3l[2][4];
#pragma unroll
  for (int m = 0; m < 2; ++m) {
    int ec = e0 + m * 16 + col; if (ec >= NE) ec = NE - 1;
    const short* ph = xch + (size_t)ec * 128 + 8 * g;
    const short* pl = xcl + (size_t)ec * 128 + 8 * g;
#pragma unroll
    for (int kf = 0; kf < 4; ++kf) {
      a3h[m][kf] = *(const short8v*)(ph + kf * 32);
      a3l[m][kf] = *(const short8v*)(pl + kf * 32);
    }
  }

  // ---- rbf A-frags for both m-tiles ----
  float dd[2];
#pragma unroll
  for (int m = 0; m < 2; ++m) {
    int ec = e0 + m * 16 + col; if (ec >= NE) ec = NE - 1;
    dd[m] = dist[ec];
  }
  short8v a1h[2][4], a1l[2][4];
#pragma unroll
  for (int m = 0; m < 2; ++m)
#pragma unroll
    for (int kf = 0; kf < 4; ++kf)
#pragma unroll
      for (int j = 0; j < 8; ++j) {
        int k = kf * 32 + 8 * g + j;
        float t = dd[m] - (float)k * (1.0f / 127.0f);
        float v = __expf(-8192.0f * t * t);
        short h, lo; f32_hilo(v, h, lo);
        a1h[m][kf][j] = h; a1l[m][kf][j] = lo;
      }

  const float4v z4 = {0.0f, 0.0f, 0.0f, 0.0f};

  // ---- GEMM1: es_raw(32x64) = rbf(32x128) @ W_rbf ----
  float4v acc1[2][4];
#pragma unroll
  for (int nt = 0; nt < 4; ++nt) {
    float4v a0 = z4, a1 = z4;
#pragma unroll
    for (int kf = 0; kf < 4; ++kf) {
      short8v bh = *(const short8v*)(Wp1h + ((nt * 4 + kf) * 64 + lane) * 8);
      short8v bl = *(const short8v*)(Wp1l + ((nt * 4 + kf) * 64 + lane) * 8);
      a0 = MFMA16(a1h[0][kf], bh, a0);
      a0 = MFMA16(a1h[0][kf], bl, a0);
      a0 = MFMA16(a1l[0][kf], bh, a0);
      a1 = MFMA16(a1h[1][kf], bh, a1);
      a1 = MFMA16(a1h[1][kf], bl, a1);
      a1 = MFMA16(a1l[1][kf], bh, a1);
    }
    acc1[0][nt] = a0; acc1[1][nt] = a1;
  }

  // ---- bias + silu -> es rows (per-wave in-order LDS) ----
  int dn_r[2][4];
#pragma unroll
  for (int m = 0; m < 2; ++m)
#pragma unroll
    for (int r = 0; r < 4; ++r) {
      int el = m * 16 + 4 * g + r;
      int sn = __shfl(idx_v, el);
      dn_r[m][r] = __shfl(idx_v, 32 + el);
      int zs = zn[sn], zd = zn[dn_r[m][r]];
#pragma unroll
      for (int nt = 0; nt < 4; ++nt) {
        float b = aemb[zs * 64 + nt * 16 + col] + aemb[zd * 64 + nt * 16 + col];
        es_s[wid][el][nt * 16 + col] = silu_f(acc1[m][nt][r] + b);
      }
    }

  // ---- GEMM2 A-frags from es rows ----
  short8v a2h[2][2], a2l[2][2];
#pragma unroll
  for (int m = 0; m < 2; ++m)
#pragma unroll
    for (int kf = 0; kf < 2; ++kf) {
      const float* p = &es_s[wid][m * 16 + col][kf * 32 + 8 * g];
      float4v v0 = *(const float4v*)p;
      float4v v1 = *(const float4v*)(p + 4);
#pragma unroll
      for (int j = 0; j < 4; ++j) {
        short h, lo;
        f32_hilo(v0[j], h, lo); a2h[m][kf][j] = h;     a2l[m][kf][j] = lo;
        f32_hilo(v1[j], h, lo); a2h[m][kf][4 + j] = h; a2l[m][kf][4 + j] = lo;
      }
    }

  // ---- GEMM2: gate = silu(es @ W_gate), store bf16 ----
  float gate_r[2][8][4];
#pragma unroll
  for (int nt = 0; nt < 8; ++nt) {
    float4v a0 = z4, a1 = z4;
#pragma unroll
    for (int kf = 0; kf < 2; ++kf) {
      short8v bh = *(const short8v*)(Wp2h + ((nt * 2 + kf) * 64 + lane) * 8);
      short8v bl = *(const short8v*)(Wp2l + ((nt * 2 + kf) * 64 + lane) * 8);
      a0 = MFMA16(a2h[0][kf], bh, a0);
      a0 = MFMA16(a2h[0][kf], bl, a0);
      a0 = MFMA16(a2l[0][kf], bh, a0);
      a1 = MFMA16(a2h[1][kf], bh, a1);
      a1 = MFMA16(a2h[1][kf], bl, a1);
      a1 = MFMA16(a2l[1][kf], bh, a1);
    }
#pragma unroll
    for (int m = 0; m < 2; ++m)
#pragma unroll
      for (int r = 0; r < 4; ++r) {
        float gv = silu_f((m == 0 ? a0 : a1)[r]);
        gate_r[m][nt][r] = gv;
        int er = e0 + m * 16 + 4 * g + r;
        if (er < NE)
          gate_ws[(size_t)er * 128 + nt * 16 + col] = __float2bfloat16(gv);
      }
  }

  // ---- GEMM3: msg0 = xcat @ W_msg ; epilogue: logits + segment-max ----
#pragma unroll
  for (int nt = 0; nt < 8; ++nt) {
    float4v a0 = z4, a1 = z4;
#pragma unroll
    for (int kf = 0; kf < 4; ++kf) {
      short8v bh = *(const short8v*)(Wp3h + ((nt * 4 + kf) * 64 + lane) * 8);
      short8v bl = *(const short8v*)(Wp3l + ((nt * 4 + kf) * 64 + lane) * 8);
      a0 = MFMA16(a3h[0][kf], bh, a0);
      a0 = MFMA16(a3h[0][kf], bl, a0);
      a0 = MFMA16(a3l[0][kf], bh, a0);
      a1 = MFMA16(a3h[1][kf], bh, a1);
      a1 = MFMA16(a3h[1][kf], bl, a1);
      a1 = MFMA16(a3l[1][kf], bh, a1);
    }
    float al = alpha[nt * 16 + col];
#pragma unroll
    for (int m = 0; m < 2; ++m)
#pragma unroll
      for (int r = 0; r < 4; ++r) {
        float v = (m == 0 ? a0 : a1)[r] * gate_r[m][nt][r];
        v = v > 0.0f ? v : 0.2f * v;
        v *= al;
#pragma unroll
        for (int off = 1; off < 16; off <<= 1) v += __shfl_xor(v, off);
        int er = e0 + m * 16 + 4 * g + r;
        if (col == 0 && er < NE) {
          logits[(size_t)er * 8 + nt] = v;
          atomicMax(&m_enc[dn_r[m][r] * 8 + nt], enc_f(v));
        }
      }
  }
}

// ---------------- pass2: den[n,h] += exp(logit - m[n,h])  [unchanged]
__global__ void pass2_kernel(const float* __restrict__ logits,
                             const int* __restrict__ ei,
                             const unsigned int* __restrict__ m_enc,
                             float* __restrict__ den) {
  int i = blockIdx.x * blockDim.x + threadIdx.x;
  if (i >= NE * 8) return;
  int e = i >> 3, h = i & 7;
  int dn = ei[NE + e];
  float mm = dec_f(m_enc[dn * 8 + h]);
  atomicAdd(&den[dn * 8 + h], __expf(logits[i] - mm));
}

// ---------------- P3a (MFMA, M=32): attn -> u -> t = u @ W_msg^T -> t_ws
__global__ __launch_bounds__(256, 2) void pass3a_kernel(
    const int* __restrict__ ei, const float* __restrict__ logits,
    const unsigned int* __restrict__ m_enc, const float* __restrict__ den,
    const __hip_bfloat16* __restrict__ gate_ws, const float* __restrict__ Q,
    const short* __restrict__ Wp4h, const short* __restrict__ Wp4l,
    float* __restrict__ t_ws) {
  __shared__ __attribute__((aligned(16))) float attn_s[4][32][8];
  __shared__ __attribute__((aligned(16))) float x_s[4][32][132];  // u
  const int tid = threadIdx.x;
  const int lane = tid & 63;
  const int wid = tid >> 6;
  const int g = lane >> 4;
  const int col = lane & 15;
  const int e0 = (blockIdx.x * 4 + wid) * 32;

  // ---- phase A: attn for 32 edges x 8 heads (4 per lane) ----
#pragma unroll
  for (int q = 0; q < 4; ++q) {
    int i = q * 64 + lane;
    int e = i >> 3, h = i & 7;
    int ec = e0 + e; if (ec >= NE) ec = NE - 1;
    int dn = ei[NE + ec];
    float l = logits[(size_t)ec * 8 + h];
    float mm = dec_f(m_enc[dn * 8 + h]);
    float dv = den[dn * 8 + h];
    attn_s[wid][e][h] = __expf(l - mm) / (dv + 1e-9f);
  }

  // ---- phase B: u[e, m] for m = 2*lane, 2*lane+1 (paired bf16 gate load) ----
  float q0[8], q1[8];
#pragma unroll
  for (int h = 0; h < 8; ++h) {
    q0[h] = Q[(2 * lane) * 8 + h];
    q1[h] = Q[(2 * lane + 1) * 8 + h];
  }
#pragma unroll 4
  for (int e = 0; e < 32; ++e) {
    int ec = e0 + e; if (ec >= NE) ec = NE - 1;
    float4v a0 = *(const float4v*)&attn_s[wid][e][0];
    float4v a1 = *(const float4v*)&attn_s[wid][e][4];
    float wv0 = 0.0f, wv1 = 0.0f;
#pragma unroll
    for (int h = 0; h < 4; ++h) {
      wv0 += q0[h] * a0[h] + q0[4 + h] * a1[h];
      wv1 += q1[h] * a0[h] + q1[4 + h] * a1[h];
    }
    unsigned int gp = *(const unsigned int*)(gate_ws + (size_t)ec * 128 + 2 * lane);
    float gg0 = __uint_as_float((gp & 0xffffu) << 16);
    float gg1 = __uint_as_float((gp & 0xffff0000u));
    float2 uu; uu.x = gg0 * wv0; uu.y = gg1 * wv1;
    *(float2*)&x_s[wid][e][2 * lane] = uu;
  }

  // ---- phase C: A-frags from u, T = U @ Wp4, t -> global ----
  short8v ah[2][4], al[2][4];
#pragma unroll
  for (int m = 0; m < 2; ++m)
#pragma unroll
    for (int kf = 0; kf < 4; ++kf) {
      const float* p = &x_s[wid][m * 16 + col][kf * 32 + 8 * g];
      float4v v0 = *(const float4v*)p;
      float4v v1 = *(const float4v*)(p + 4);
#pragma unroll
      for (int j = 0; j < 4; ++j) {
        short h, lo;
        f32_hilo(v0[j], h, lo); ah[m][kf][j] = h;     al[m][kf][j] = lo;
        f32_hilo(v1[j], h, lo); ah[m][kf][4 + j] = h; al[m][kf][4 + j] = lo;
      }
    }
  const float4v z4 = {0.0f, 0.0f, 0.0f, 0.0f};
#pragma unroll
  for (int nt = 0; nt < 8; ++nt) {
    float4v a0 = z4, a1 = z4;
#pragma unroll
    for (int kf = 0; kf < 4; ++kf) {
      short8v bh = *(const short8v*)(Wp4h + ((nt * 4 + kf) * 64 + lane) * 8);
      short8v bl = *(const short8v*)(Wp4l + ((nt * 4 + kf) * 64 + lane) * 8);
      a0 = MFMA16(ah[0][kf], bh, a0);
      a0 = MFMA16(ah[0][kf], bl, a0);
      a0 = MFMA16(al[0][kf], bh, a0);
      a1 = MFMA16(ah[1][kf], bh, a1);
      a1 = MFMA16(ah[1][kf], bl, a1);
      a1 = MFMA16(al[1][kf], bh, a1);
    }
#pragma unroll
    for (int m = 0; m < 2; ++m)
#pragma unroll
      for (int r = 0; r < 4; ++r) {
        int er = e0 + m * 16 + 4 * g + r;
        if (er < NE)
          t_ws[(size_t)er * 128 + nt * 16 + col] = (m == 0 ? a0 : a1)[r];
      }
  }
}

// ---------------- P3b: one wave per edge; gather + 9 dots + wigner epilogue
__global__ __launch_bounds__(256) void pass3b_kernel(
    const float* __restrict__ nb, const int* __restrict__ ei,
    const float* __restrict__ wig, const float* __restrict__ t_ws,
    float* __restrict__ out) {
  const int lane = threadIdx.x & 63;
  const int e = blockIdx.x * 4 + (threadIdx.x >> 6);  // NE % 4 == 0
  int se = ei[e], de = ei[NE + e];
  float t0 = t_ws[(size_t)e * 128 + lane];
  float t1 = t_ws[(size_t)e * 128 + 64 + lane];
  const float* __restrict__ ps = nb + (size_t)se * 576 + lane;
  const float* __restrict__ pt = nb + (size_t)de * 576 + lane;
  float p[9];
#pragma unroll
  for (int j = 0; j < 9; ++j)
    p[j] = ps[j * 64] * t0 + pt[j * 64] * t1;
  // full 64-lane butterfly; afterwards every lane holds d[j]
#pragma unroll
  for (int off = 1; off < 64; off <<= 1)
#pragma unroll
    for (int j = 0; j < 9; ++j) p[j] += __shfl_xor(p[j], off);

  const float* __restrict__ we = wig + (size_t)e * 81;
  int ls = lane < 9 ? lane : 8;
  float s_l = 0.0f;
#pragma unroll
  for (int jp = 0; jp < 9; ++jp) s_l += we[ls * 9 + jp] * p[jp];
  int lc = (lane >= 1 && lane <= 3) ? lane : 1;
  float f = 0.0f;
#pragma unroll
  for (int j = 0; j < 9; ++j)
    f += __shfl(s_l, j) * we[j * 9 + lc];
  if (lane >= 1 && lane <= 3)
    atomicAdd(&out[de * 3 + (lane - 1)], f);
}

extern "C" void kernel_launch(void* const* d_in, const int* in_sizes, int n_in,
                              void* d_out, int out_size, void* d_ws, size_t ws_size,
                              hipStream_t stream) {
  const float* nb = (const float*)d_in[0];
  const int* zn = (const int*)d_in[1];
  const float* dist = (const float*)d_in[2];
  const int* ei = (const int*)d_in[3];
  const float* wig = (const float*)d_in[4];
  const float* aemb = (const float*)d_in[5];
  const float* W_rbf = (const float*)d_in[6];
  const float* W_gate = (const float*)d_in[7];
  const float* W_msg = (const float*)d_in[8];
  const float* alpha = (const float*)d_in[9];
  const float* W_val = (const float*)d_in[10];
  const float* W_out = (const float*)d_in[11];
  float* out = (float*)d_out;

  // workspace layout (~81 MB)
  char* p = (char*)d_ws;
  float* Q = (float*)p;                   p += 1024 * 4;
  unsigned int* m_enc = (unsigned int*)p; p += (size_t)NN * 8 * 4;
  float* den = (float*)p;                 p += (size_t)NN * 8 * 4;
  float* logits = (float*)p;              p += (size_t)NE * 8 * 4;
  __hip_bfloat16* gate_ws = (__hip_bfloat16*)p; p += (size_t)NE * 128 * 2;
  short* Wp1h = (short*)p; p += 8192 * 2;
  short* Wp1l = (short*)p; p += 8192 * 2;
  short* Wp2h = (short*)p; p += 8192 * 2;
  short* Wp2l = (short*)p; p += 8192 * 2;
  short* Wp3h = (short*)p; p += 16384 * 2;
  short* Wp3l = (short*)p; p += 16384 * 2;
  short* Wp4h = (short*)p; p += 16384 * 2;
  short* Wp4l = (short*)p; p += 16384 * 2;
  short* xch = (short*)p;                 p += (size_t)NE * 128 * 2;
  short* xcl = (short*)p;                 p += (size_t)NE * 128 * 2;
  float* t_ws = (float*)xch;  // aliased: xc consumed by P1 before P3a writes t

  hipMemsetAsync(d_out, 0, (size_t)NN * 3 * 4, stream);
  hipMemsetAsync(m_enc, 0, (size_t)NN * 8 * 4, stream);
  hipMemsetAsync(den, 0, (size_t)NN * 8 * 4, stream);

  prep_kernel<<<192, 256, 0, stream>>>(W_msg, W_val, W_out, W_rbf, W_gate, Q,
                                       Wp1h, Wp1l, Wp2h, Wp2l, Wp3h, Wp3l, Wp4h, Wp4l);
  gather1_kernel<<<NE / 4, 256, 0, stream>>>(nb, ei, wig, xch, xcl);
  pass1_kernel<<<(NE + 127) / 128, 256, 0, stream>>>(zn, dist, ei, aemb, alpha,
                                                     xch, xcl,
                                                     Wp1h, Wp1l, Wp2h, Wp2l, Wp3h, Wp3l,
                                                     logits, m_enc, gate_ws);
  pass2_kernel<<<(NE * 8 + 255) / 256, 256, 0, stream>>>(logits, ei, m_enc, den);
  pass3a_kernel<<<(NE + 127) / 128, 256, 0, stream>>>(ei, logits, m_enc, den,
                                                      gate_ws, Q, Wp4h, Wp4l, t_ws);
  pass3b_kernel<<<NE / 4, 256, 0, stream>>>(nb, ei, wig, t_ws, out);
}

// Round 8
// 315.265 us; speedup vs baseline: 1.1455x; 1.1455x over previous
//
#include <hip/hip_runtime.h>
#include <hip/hip_bf16.h>

#define NN 10000
#define NE 100000

typedef __attribute__((ext_vector_type(8))) short short8v;
typedef __attribute__((ext_vector_type(4))) short short4v;
typedef __attribute__((ext_vector_type(4))) float float4v;

__device__ __forceinline__ unsigned int enc_f(float f) {
  unsigned int u = __float_as_uint(f);
  return (u & 0x80000000u) ? ~u : (u | 0x80000000u);
}
__device__ __forceinline__ float dec_f(unsigned int u) {
  return __uint_as_float((u & 0x80000000u) ? (u & 0x7fffffffu) : ~u);
}
__device__ __forceinline__ float silu_f(float x) {
  return x / (1.0f + __expf(-x));
}
__device__ __forceinline__ float b2f(short s) {
  return __uint_as_float(((unsigned int)(unsigned short)s) << 16);
}
// fp32 -> bf16 hi/lo split: x ~= hi + lo with ~2^-16 relative error.
__device__ __forceinline__ void f32_hilo(float x, short& h, short& l) {
  __hip_bfloat16 bh = __float2bfloat16(x);
  float r = x - __bfloat162float(bh);
  __hip_bfloat16 bl = __float2bfloat16(r);
  h = __builtin_bit_cast(short, bh);
  l = __builtin_bit_cast(short, bl);
}
__device__ __forceinline__ short f2bf(float x) {
  return __builtin_bit_cast(short, __float2bfloat16(x));
}
#define MFMA16(a, b, c) __builtin_amdgcn_mfma_f32_16x16x32_bf16(a, b, c, 0, 0, 0)

// ---------------- prep: Q + MFMA weight fragment packs (unchanged).
__global__ void prep_kernel(const float* __restrict__ W_msg, const float* __restrict__ W_val,
                            const float* __restrict__ W_out, const float* __restrict__ W_rbf,
                            const float* __restrict__ W_gate,
                            float* __restrict__ Q,
                            short* __restrict__ Wp1h, short* __restrict__ Wp1l,
                            short* __restrict__ Wp2h, short* __restrict__ Wp2l,
                            short* __restrict__ Wp3h, short* __restrict__ Wp3l,
                            short* __restrict__ Wp4h, short* __restrict__ Wp4l) {
  int i = blockIdx.x * blockDim.x + threadIdx.x;  // grid = 192*256 = 49152
  if (i < 1024) {
    int c = i >> 3, h = i & 7;
    float s = 0.0f;
#pragma unroll
    for (int dv = 0; dv < 16; ++dv)
      s += W_val[c * 128 + h * 16 + dv] * W_out[h * 16 + dv];
    Q[c * 8 + h] = s;
  }
  const float* W; short* ph; short* pl; int KF, Nw, local; bool tr = false;
  if (i < 8192)       { W = W_rbf;  ph = Wp1h; pl = Wp1l; KF = 4; Nw = 64;  local = i; }
  else if (i < 16384) { W = W_gate; ph = Wp2h; pl = Wp2l; KF = 2; Nw = 128; local = i - 8192; }
  else if (i < 32768) { W = W_msg;  ph = Wp3h; pl = Wp3l; KF = 4; Nw = 128; local = i - 16384; }
  else                { W = W_msg;  ph = Wp4h; pl = Wp4l; KF = 4; Nw = 128; local = i - 32768; tr = true; }
  int tile = local >> 9;           // nt*KF + kf
  int ln = (local >> 3) & 63;
  int j = local & 7;
  int nt = tile / KF, kf = tile % KF;
  int k = kf * 32 + 8 * (ln >> 4) + j;
  int n = nt * 16 + (ln & 15);
  float w = tr ? W[n * 128 + k] : W[k * Nw + n];
  short h, lo;
  f32_hilo(w, h, lo);
  ph[local] = h;
  pl[local] = lo;
}

// ---------------- G1: one wave per edge. Computes the FULL 9-row wig
// transform xs/xt, emits:
//   xch/xcl: row-0 concat as bf16 hi/lo (P1's A3 frags)
//   Gb:      per-edge force matrices Gs_i[c]=sum_j wig[j,i]*xs_j[c] (i=1..3)
//            and Gt_i (bf16, [e][6][64]) -> the force epilogue becomes
//            a pure streaming dot (no nb/wig re-read anywhere else).
__global__ __launch_bounds__(256) void gather1_kernel(
    const float* __restrict__ nb, const int* __restrict__ ei,
    const float* __restrict__ wig, short* __restrict__ xch,
    short* __restrict__ xcl, short* __restrict__ Gb) {
  const int lane = threadIdx.x & 63;
  const int e = blockIdx.x * 4 + (threadIdx.x >> 6);  // NE % 4 == 0
  int se = ei[e], de = ei[NE + e];
  const float* __restrict__ pw = wig + (size_t)e * 81;
  const float* __restrict__ ps = nb + (size_t)se * 576 + lane;
  const float* __restrict__ pt = nb + (size_t)de * 576 + lane;
  float vs[9], vt[9];
#pragma unroll
  for (int j = 0; j < 9; ++j) {
    vs[j] = ps[j * 64];
    vt[j] = pt[j * 64];
  }
  float Gs0 = 0, Gs1 = 0, Gs2 = 0, Gt0 = 0, Gt1 = 0, Gt2 = 0;
#pragma unroll
  for (int j = 0; j < 9; ++j) {
    float row[9];
#pragma unroll
    for (int jp = 0; jp < 9; ++jp) row[jp] = pw[j * 9 + jp];  // wave-uniform
    float xs = 0.0f, xt = 0.0f;
#pragma unroll
    for (int jp = 0; jp < 9; ++jp) { xs += row[jp] * vs[jp]; xt += row[jp] * vt[jp]; }
    if (j == 0) {  // row-0 concat -> P1 A-frag pack
      short h, l;
      f32_hilo(xs, h, l);
      xch[(size_t)e * 128 + lane] = h;
      xcl[(size_t)e * 128 + lane] = l;
      f32_hilo(xt, h, l);
      xch[(size_t)e * 128 + 64 + lane] = h;
      xcl[(size_t)e * 128 + 64 + lane] = l;
    }
    Gs0 += row[1] * xs; Gs1 += row[2] * xs; Gs2 += row[3] * xs;
    Gt0 += row[1] * xt; Gt1 += row[2] * xt; Gt2 += row[3] * xt;
  }
  short* gp = Gb + (size_t)e * 384 + lane;
  gp[0]       = f2bf(Gs0);
  gp[64]      = f2bf(Gs1);
  gp[128]     = f2bf(Gs2);
  gp[192]     = f2bf(Gt0);
  gp[256]     = f2bf(Gt1);
  gp[320]     = f2bf(Gt2);
}

// ---------------- P1 (MFMA, M=16, r6 structure): gate, logits, segment-max.
// A3 frags are raw 16B loads from xch/xcl.
__global__ __launch_bounds__(256, 3) void pass1_kernel(
    const int* __restrict__ zn, const float* __restrict__ dist,
    const int* __restrict__ ei, const float* __restrict__ aemb,
    const float* __restrict__ alpha,
    const short* __restrict__ xch, const short* __restrict__ xcl,
    const short* __restrict__ Wp1h, const short* __restrict__ Wp1l,
    const short* __restrict__ Wp2h, const short* __restrict__ Wp2l,
    const short* __restrict__ Wp3h, const short* __restrict__ Wp3l,
    float* __restrict__ logits, unsigned int* __restrict__ m_enc,
    __hip_bfloat16* __restrict__ gate_ws) {
  __shared__ __attribute__((aligned(16))) float es_s[4][16][68];
  const int tid = threadIdx.x;
  const int lane = tid & 63;
  const int wid = tid >> 6;
  const int g = lane >> 4;
  const int col = lane & 15;
  const int e0 = (blockIdx.x * 4 + wid) * 16;

  // wave's 32 edge indices: lanes 0..15 = src, 16..31 = dst
  int l16 = lane & 15;
  int ecl16 = (e0 + l16 < NE) ? e0 + l16 : NE - 1;
  int idx_v = 0;
  if (lane < 32) idx_v = ei[(lane < 16 ? 0 : NE) + ecl16];

  int ecol = e0 + col; if (ecol >= NE) ecol = NE - 1;
  const float d = dist[ecol];

  // ---- A3 frags: raw 16B loads from packed xc (issued first) ----
  const short* ph = xch + (size_t)ecol * 128 + 8 * g;
  const short* pl = xcl + (size_t)ecol * 128 + 8 * g;
  short8v a3h[4], a3l[4];
#pragma unroll
  for (int kf = 0; kf < 4; ++kf) {
    a3h[kf] = *(const short8v*)(ph + kf * 32);
    a3l[kf] = *(const short8v*)(pl + kf * 32);
  }

  // ---- rbf A-frags (direct in fragment layout) ----
  short8v a1h[4], a1l[4];
#pragma unroll
  for (int kf = 0; kf < 4; ++kf) {
#pragma unroll
    for (int j = 0; j < 8; ++j) {
      int k = kf * 32 + 8 * g + j;
      float t = d - (float)k * (1.0f / 127.0f);
      float v = __expf(-8192.0f * t * t);
      short h, lo; f32_hilo(v, h, lo);
      a1h[kf][j] = h; a1l[kf][j] = lo;
    }
  }

  const float4v z4 = {0.0f, 0.0f, 0.0f, 0.0f};

  // ---- GEMM1: es_raw(16x64) = rbf(16x128) @ W_rbf ----
  float4v acc1[4];
#pragma unroll
  for (int nt = 0; nt < 4; ++nt) {
    float4v a = z4;
#pragma unroll
    for (int kf = 0; kf < 4; ++kf) {
      short8v bh = *(const short8v*)(Wp1h + ((nt * 4 + kf) * 64 + lane) * 8);
      short8v bl = *(const short8v*)(Wp1l + ((nt * 4 + kf) * 64 + lane) * 8);
      a = MFMA16(a1h[kf], bh, a);
      a = MFMA16(a1h[kf], bl, a);
      a = MFMA16(a1l[kf], bh, a);
    }
    acc1[nt] = a;
  }

  // ---- bias + silu -> es rows (per-wave in-order LDS) ----
  int dn_r[4];
#pragma unroll
  for (int r = 0; r < 4; ++r) {
    int sn = __shfl(idx_v, 4 * g + r);
    dn_r[r] = __shfl(idx_v, 16 + 4 * g + r);
    int zs = zn[sn], zd = zn[dn_r[r]];
#pragma unroll
    for (int nt = 0; nt < 4; ++nt) {
      float b = aemb[zs * 64 + nt * 16 + col] + aemb[zd * 64 + nt * 16 + col];
      es_s[wid][4 * g + r][nt * 16 + col] = silu_f(acc1[nt][r] + b);
    }
  }

  // ---- GEMM2 A-frags from es rows ----
  short8v a2h[2], a2l[2];
#pragma unroll
  for (int kf = 0; kf < 2; ++kf) {
    const float* p = &es_s[wid][col][kf * 32 + 8 * g];
    float4v v0 = *(const float4v*)p;
    float4v v1 = *(const float4v*)(p + 4);
#pragma unroll
    for (int j = 0; j < 4; ++j) {
      short h, lo;
      f32_hilo(v0[j], h, lo); a2h[kf][j] = h;     a2l[kf][j] = lo;
      f32_hilo(v1[j], h, lo); a2h[kf][4 + j] = h; a2l[kf][4 + j] = lo;
    }
  }

  // ---- GEMM2: gate = silu(es @ W_gate), store bf16 ----
  float gate_r[8][4];
#pragma unroll
  for (int nt = 0; nt < 8; ++nt) {
    float4v a = z4;
#pragma unroll
    for (int kf = 0; kf < 2; ++kf) {
      short8v bh = *(const short8v*)(Wp2h + ((nt * 2 + kf) * 64 + lane) * 8);
      short8v bl = *(const short8v*)(Wp2l + ((nt * 2 + kf) * 64 + lane) * 8);
      a = MFMA16(a2h[kf], bh, a);
      a = MFMA16(a2h[kf], bl, a);
      a = MFMA16(a2l[kf], bh, a);
    }
#pragma unroll
    for (int r = 0; r < 4; ++r) {
      float gv = silu_f(a[r]);
      gate_r[nt][r] = gv;
      int er = e0 + 4 * g + r;
      if (er < NE)
        gate_ws[(size_t)er * 128 + nt * 16 + col] = __float2bfloat16(gv);
    }
  }

  // ---- GEMM3: msg0 = xcat @ W_msg ; epilogue: logits + segment-max ----
#pragma unroll
  for (int nt = 0; nt < 8; ++nt) {
    float4v a = z4;
#pragma unroll
    for (int kf = 0; kf < 4; ++kf) {
      short8v bh = *(const short8v*)(Wp3h + ((nt * 4 + kf) * 64 + lane) * 8);
      short8v bl = *(const short8v*)(Wp3l + ((nt * 4 + kf) * 64 + lane) * 8);
      a = MFMA16(a3h[kf], bh, a);
      a = MFMA16(a3h[kf], bl, a);
      a = MFMA16(a3l[kf], bh, a);
    }
    float al = alpha[nt * 16 + col];
#pragma unroll
    for (int r = 0; r < 4; ++r) {
      float v = a[r] * gate_r[nt][r];
      v = v > 0.0f ? v : 0.2f * v;
      v *= al;
#pragma unroll
      for (int off = 1; off < 16; off <<= 1) v += __shfl_xor(v, off);
      int er = e0 + 4 * g + r;
      if (col == 0 && er < NE) {
        logits[(size_t)er * 8 + nt] = v;
        atomicMax(&m_enc[dn_r[r] * 8 + nt], enc_f(v));
      }
    }
  }
}

// ---------------- pass2: den[n,h] += exp(logit - m[n,h])  [unchanged]
__global__ void pass2_kernel(const float* __restrict__ logits,
                             const int* __restrict__ ei,
                             const unsigned int* __restrict__ m_enc,
                             float* __restrict__ den) {
  int i = blockIdx.x * blockDim.x + threadIdx.x;
  if (i >= NE * 8) return;
  int e = i >> 3, h = i & 7;
  int dn = ei[NE + e];
  float mm = dec_f(m_enc[dn * 8 + h]);
  atomicAdd(&den[dn * 8 + h], __expf(logits[i] - mm));
}

// ---------------- pass3 (fused, M=16): attn -> u -> t (MFMA) -> forces.
// Force phase reads only the streaming Gb: zero random access.
__global__ __launch_bounds__(256, 3) void pass3_kernel(
    const int* __restrict__ ei, const float* __restrict__ logits,
    const unsigned int* __restrict__ m_enc, const float* __restrict__ den,
    const __hip_bfloat16* __restrict__ gate_ws, const float* __restrict__ Q,
    const short* __restrict__ Wp4h, const short* __restrict__ Wp4l,
    const short* __restrict__ Gb, float* __restrict__ out) {
  __shared__ __attribute__((aligned(16))) float attn_s[4][16][8];
  __shared__ __attribute__((aligned(16))) float x_s[4][16][132];  // u, then t
  const int tid = threadIdx.x;
  const int lane = tid & 63;
  const int wid = tid >> 6;
  const int g = lane >> 4;
  const int col = lane & 15;
  const int e0 = (blockIdx.x * 4 + wid) * 16;

  // ---- phase A: attn for 16 edges x 8 heads ----
#pragma unroll
  for (int half = 0; half < 2; ++half) {
    int i = half * 64 + lane;
    int e = i >> 3, h = i & 7;
    int ec = e0 + e; if (ec >= NE) ec = NE - 1;
    int dn = ei[NE + ec];
    float l = logits[(size_t)ec * 8 + h];
    float mm = dec_f(m_enc[dn * 8 + h]);
    float dv = den[dn * 8 + h];
    attn_s[wid][e][h] = __expf(l - mm) / (dv + 1e-9f);
  }

  // ---- phase B: u[e, m] for m = 2*lane, 2*lane+1 (paired bf16 gate load) ----
  float q0[8], q1[8];
#pragma unroll
  for (int h = 0; h < 8; ++h) {
    q0[h] = Q[(2 * lane) * 8 + h];
    q1[h] = Q[(2 * lane + 1) * 8 + h];
  }
#pragma unroll 4
  for (int e = 0; e < 16; ++e) {
    int ec = e0 + e; if (ec >= NE) ec = NE - 1;
    float4v a0 = *(const float4v*)&attn_s[wid][e][0];
    float4v a1 = *(const float4v*)&attn_s[wid][e][4];
    float wv0 = 0.0f, wv1 = 0.0f;
#pragma unroll
    for (int h = 0; h < 4; ++h) {
      wv0 += q0[h] * a0[h] + q0[4 + h] * a1[h];
      wv1 += q1[h] * a0[h] + q1[4 + h] * a1[h];
    }
    unsigned int gp = *(const unsigned int*)(gate_ws + (size_t)ec * 128 + 2 * lane);
    float gg0 = __uint_as_float((gp & 0xffffu) << 16);
    float gg1 = __uint_as_float((gp & 0xffff0000u));
    float2 uu; uu.x = gg0 * wv0; uu.y = gg1 * wv1;
    *(float2*)&x_s[wid][e][2 * lane] = uu;
  }

  // ---- phase C: A-frags from u, T = U @ Wp4 (96 MFMA), t -> x_s ----
  short8v ah[4], al[4];
#pragma unroll
  for (int kf = 0; kf < 4; ++kf) {
    const float* p = &x_s[wid][col][kf * 32 + 8 * g];
    float4v v0 = *(const float4v*)p;
    float4v v1 = *(const float4v*)(p + 4);
#pragma unroll
    for (int j = 0; j < 4; ++j) {
      short h, lo;
      f32_hilo(v0[j], h, lo); ah[kf][j] = h;     al[kf][j] = lo;
      f32_hilo(v1[j], h, lo); ah[kf][4 + j] = h; al[kf][4 + j] = lo;
    }
  }
  const float4v z4 = {0.0f, 0.0f, 0.0f, 0.0f};
#pragma unroll
  for (int nt = 0; nt < 8; ++nt) {
    float4v a = z4;
#pragma unroll
    for (int kf = 0; kf < 4; ++kf) {
      short8v bh = *(const short8v*)(Wp4h + ((nt * 4 + kf) * 64 + lane) * 8);
      short8v bl = *(const short8v*)(Wp4l + ((nt * 4 + kf) * 64 + lane) * 8);
      a = MFMA16(ah[kf], bh, a);
      a = MFMA16(ah[kf], bl, a);
      a = MFMA16(al[kf], bh, a);
    }
#pragma unroll
    for (int r = 0; r < 4; ++r)
      x_s[wid][4 * g + r][nt * 16 + col] = a[r];
  }

  // ---- phase D: forces from Gb (streaming) ; 4 edges parallel, 16 lanes each ----
  const int cg = col * 4;  // 4 channels per lane
#pragma unroll
  for (int it = 0; it < 4; ++it) {
    int e = it * 4 + g;
    int eu = e0 + e;
    bool valid = eu < NE;
    int ec = valid ? eu : NE - 1;
    int de = ei[NE + ec];
    float4v t0 = *(const float4v*)&x_s[wid][e][cg];
    float4v t1 = *(const float4v*)&x_s[wid][e][64 + cg];
    const short* gp = Gb + (size_t)ec * 384 + cg;
    float p[3];
#pragma unroll
    for (int i = 0; i < 3; ++i) {
      short4v gs = *(const short4v*)(gp + i * 64);
      short4v gt = *(const short4v*)(gp + (3 + i) * 64);
      p[i] = b2f(gs[0]) * t0[0] + b2f(gs[1]) * t0[1] + b2f(gs[2]) * t0[2] + b2f(gs[3]) * t0[3] +
             b2f(gt[0]) * t1[0] + b2f(gt[1]) * t1[1] + b2f(gt[2]) * t1[2] + b2f(gt[3]) * t1[3];
    }
#pragma unroll
    for (int i = 0; i < 3; ++i)
#pragma unroll
      for (int off = 1; off < 16; off <<= 1) p[i] += __shfl_xor(p[i], off);
    float pv = (col == 1) ? p[0] : ((col == 2) ? p[1] : p[2]);
    if (valid && col >= 1 && col <= 3)
      atomicAdd(&out[de * 3 + (col - 1)], pv);
  }
}

extern "C" void kernel_launch(void* const* d_in, const int* in_sizes, int n_in,
                              void* d_out, int out_size, void* d_ws, size_t ws_size,
                              hipStream_t stream) {
  const float* nb = (const float*)d_in[0];
  const int* zn = (const int*)d_in[1];
  const float* dist = (const float*)d_in[2];
  const int* ei = (const int*)d_in[3];
  const float* wig = (const float*)d_in[4];
  const float* aemb = (const float*)d_in[5];
  const float* W_rbf = (const float*)d_in[6];
  const float* W_gate = (const float*)d_in[7];
  const float* W_msg = (const float*)d_in[8];
  const float* alpha = (const float*)d_in[9];
  const float* W_val = (const float*)d_in[10];
  const float* W_out = (const float*)d_in[11];
  float* out = (float*)d_out;

  // workspace layout (~158 MB)
  char* p = (char*)d_ws;
  float* Q = (float*)p;                   p += 1024 * 4;
  unsigned int* m_enc = (unsigned int*)p; p += (size_t)NN * 8 * 4;
  float* den = (float*)p;                 p += (size_t)NN * 8 * 4;
  float* logits = (float*)p;              p += (size_t)NE * 8 * 4;
  __hip_bfloat16* gate_ws = (__hip_bfloat16*)p; p += (size_t)NE * 128 * 2;
  short* Wp1h = (short*)p; p += 8192 * 2;
  short* Wp1l = (short*)p; p += 8192 * 2;
  short* Wp2h = (short*)p; p += 8192 * 2;
  short* Wp2l = (short*)p; p += 8192 * 2;
  short* Wp3h = (short*)p; p += 16384 * 2;
  short* Wp3l = (short*)p; p += 16384 * 2;
  short* Wp4h = (short*)p; p += 16384 * 2;
  short* Wp4l = (short*)p; p += 16384 * 2;
  short* xch = (short*)p;                 p += (size_t)NE * 128 * 2;
  short* xcl = (short*)p;                 p += (size_t)NE * 128 * 2;
  short* Gb = (short*)p;                  p += (size_t)NE * 384 * 2;

  hipMemsetAsync(d_out, 0, (size_t)NN * 3 * 4, stream);
  hipMemsetAsync(m_enc, 0, (size_t)NN * 8 * 4, stream);
  hipMemsetAsync(den, 0, (size_t)NN * 8 * 4, stream);

  prep_kernel<<<192, 256, 0, stream>>>(W_msg, W_val, W_out, W_rbf, W_gate, Q,
                                       Wp1h, Wp1l, Wp2h, Wp2l, Wp3h, Wp3l, Wp4h, Wp4l);
  gather1_kernel<<<NE / 4, 256, 0, stream>>>(nb, ei, wig, xch, xcl, Gb);
  pass1_kernel<<<(NE + 63) / 64, 256, 0, stream>>>(zn, dist, ei, aemb, alpha,
                                                   xch, xcl,
                                                   Wp1h, Wp1l, Wp2h, Wp2l, Wp3h, Wp3l,
                                                   logits, m_enc, gate_ws);
  pass2_kernel<<<(NE * 8 + 255) / 256, 256, 0, stream>>>(logits, ei, m_enc, den);
  pass3_kernel<<<(NE + 63) / 64, 256, 0, stream>>>(ei, logits, m_enc, den,
                                                   gate_ws, Q, Wp4h, Wp4l, Gb, out);
}

// Round 9
// 309.654 us; speedup vs baseline: 1.1663x; 1.0181x over previous
//
#include <hip/hip_runtime.h>
#include <hip/hip_bf16.h>

#define NN 10000
#define NE 100000

typedef __attribute__((ext_vector_type(8))) short short8v;
typedef __attribute__((ext_vector_type(4))) short short4v;
typedef __attribute__((ext_vector_type(4))) float float4v;

__device__ __forceinline__ unsigned int enc_f(float f) {
  unsigned int u = __float_as_uint(f);
  return (u & 0x80000000u) ? ~u : (u | 0x80000000u);
}
__device__ __forceinline__ float dec_f(unsigned int u) {
  return __uint_as_float((u & 0x80000000u) ? (u & 0x7fffffffu) : ~u);
}
__device__ __forceinline__ float silu_f(float x) {
  return x / (1.0f + __expf(-x));
}
__device__ __forceinline__ float b2f(short s) {
  return __uint_as_float(((unsigned int)(unsigned short)s) << 16);
}
// fp32 -> bf16 hi/lo split: x ~= hi + lo with ~2^-16 relative error.
__device__ __forceinline__ void f32_hilo(float x, short& h, short& l) {
  __hip_bfloat16 bh = __float2bfloat16(x);
  float r = x - __bfloat162float(bh);
  __hip_bfloat16 bl = __float2bfloat16(r);
  h = __builtin_bit_cast(short, bh);
  l = __builtin_bit_cast(short, bl);
}
__device__ __forceinline__ short f2bf(float x) {
  return __builtin_bit_cast(short, __float2bfloat16(x));
}
#define MFMA16(a, b, c) __builtin_amdgcn_mfma_f32_16x16x32_bf16(a, b, c, 0, 0, 0)

// ---------------- prep: Q + MFMA weight fragment packs (unchanged).
__global__ void prep_kernel(const float* __restrict__ W_msg, const float* __restrict__ W_val,
                            const float* __restrict__ W_out, const float* __restrict__ W_rbf,
                            const float* __restrict__ W_gate,
                            float* __restrict__ Q,
                            short* __restrict__ Wp1h, short* __restrict__ Wp1l,
                            short* __restrict__ Wp2h, short* __restrict__ Wp2l,
                            short* __restrict__ Wp3h, short* __restrict__ Wp3l,
                            short* __restrict__ Wp4h, short* __restrict__ Wp4l) {
  int i = blockIdx.x * blockDim.x + threadIdx.x;  // grid = 192*256 = 49152
  if (i < 1024) {
    int c = i >> 3, h = i & 7;
    float s = 0.0f;
#pragma unroll
    for (int dv = 0; dv < 16; ++dv)
      s += W_val[c * 128 + h * 16 + dv] * W_out[h * 16 + dv];
    Q[c * 8 + h] = s;
  }
  const float* W; short* ph; short* pl; int KF, Nw, local; bool tr = false;
  if (i < 8192)       { W = W_rbf;  ph = Wp1h; pl = Wp1l; KF = 4; Nw = 64;  local = i; }
  else if (i < 16384) { W = W_gate; ph = Wp2h; pl = Wp2l; KF = 2; Nw = 128; local = i - 8192; }
  else if (i < 32768) { W = W_msg;  ph = Wp3h; pl = Wp3l; KF = 4; Nw = 128; local = i - 16384; }
  else                { W = W_msg;  ph = Wp4h; pl = Wp4l; KF = 4; Nw = 128; local = i - 32768; tr = true; }
  int tile = local >> 9;           // nt*KF + kf
  int ln = (local >> 3) & 63;
  int j = local & 7;
  int nt = tile / KF, kf = tile % KF;
  int k = kf * 32 + 8 * (ln >> 4) + j;
  int n = nt * 16 + (ln & 15);
  float w = tr ? W[n * 128 + k] : W[k * Nw + n];
  short h, lo;
  f32_hilo(w, h, lo);
  ph[local] = h;
  pl[local] = lo;
}

// ---------------- G1: TWO edges per wave (36 row-loads in flight).
// Computes the full 9-row wig transform; emits xch/xcl (row-0 concat, bf16
// hi/lo = P1's A-frags) and Gb (per-edge force matrices, bf16).
__global__ __launch_bounds__(256) void gather1_kernel(
    const float* __restrict__ nb, const int* __restrict__ ei,
    const float* __restrict__ wig, short* __restrict__ xch,
    short* __restrict__ xcl, short* __restrict__ Gb) {
  const int lane = threadIdx.x & 63;
  const int e0 = blockIdx.x * 8 + (threadIdx.x >> 6) * 2;  // NE % 8 == 0
  int se0 = ei[e0],     de0 = ei[NE + e0];
  int se1 = ei[e0 + 1], de1 = ei[NE + e0 + 1];
  const float* __restrict__ ps0 = nb + (size_t)se0 * 576 + lane;
  const float* __restrict__ pt0 = nb + (size_t)de0 * 576 + lane;
  const float* __restrict__ ps1 = nb + (size_t)se1 * 576 + lane;
  const float* __restrict__ pt1 = nb + (size_t)de1 * 576 + lane;
  float vs0[9], vt0[9], vs1[9], vt1[9];
#pragma unroll
  for (int j = 0; j < 9; ++j) {
    vs0[j] = ps0[j * 64];
    vt0[j] = pt0[j * 64];
    vs1[j] = ps1[j * 64];
    vt1[j] = pt1[j * 64];
  }
#pragma unroll
  for (int ee = 0; ee < 2; ++ee) {
    const int e = e0 + ee;
    const float* __restrict__ pw = wig + (size_t)e * 81;
    float* vs = ee ? vs1 : vs0;
    float* vt = ee ? vt1 : vt0;
    float Gs0 = 0, Gs1 = 0, Gs2 = 0, Gt0 = 0, Gt1 = 0, Gt2 = 0;
#pragma unroll
    for (int j = 0; j < 9; ++j) {
      float row[9];
#pragma unroll
      for (int jp = 0; jp < 9; ++jp) row[jp] = pw[j * 9 + jp];  // wave-uniform
      float xs = 0.0f, xt = 0.0f;
#pragma unroll
      for (int jp = 0; jp < 9; ++jp) { xs += row[jp] * vs[jp]; xt += row[jp] * vt[jp]; }
      if (j == 0) {  // row-0 concat -> P1 A-frag pack
        short h, l;
        f32_hilo(xs, h, l);
        xch[(size_t)e * 128 + lane] = h;
        xcl[(size_t)e * 128 + lane] = l;
        f32_hilo(xt, h, l);
        xch[(size_t)e * 128 + 64 + lane] = h;
        xcl[(size_t)e * 128 + 64 + lane] = l;
      }
      Gs0 += row[1] * xs; Gs1 += row[2] * xs; Gs2 += row[3] * xs;
      Gt0 += row[1] * xt; Gt1 += row[2] * xt; Gt2 += row[3] * xt;
    }
    short* gp = Gb + (size_t)e * 384 + lane;
    gp[0]   = f2bf(Gs0);
    gp[64]  = f2bf(Gs1);
    gp[128] = f2bf(Gs2);
    gp[192] = f2bf(Gt0);
    gp[256] = f2bf(Gt1);
    gp[320] = f2bf(Gt2);
  }
}

// ---------------- P1 (MFMA, M=16) with LDS-staged weights: the block's 4
// waves share ONE copy of each Wp pack (L2 B-frag traffic /4 per wave ->
// /16 net). 8-barrier schedule; math identical to r6/r8.
__global__ __launch_bounds__(256, 3) void pass1_kernel(
    const int* __restrict__ zn, const float* __restrict__ dist,
    const int* __restrict__ ei, const float* __restrict__ aemb,
    const float* __restrict__ alpha,
    const short* __restrict__ xch, const short* __restrict__ xcl,
    const short* __restrict__ Wp1h, const short* __restrict__ Wp1l,
    const short* __restrict__ Wp2h, const short* __restrict__ Wp2l,
    const short* __restrict__ Wp3h, const short* __restrict__ Wp3l,
    float* __restrict__ logits, unsigned int* __restrict__ m_enc,
    __hip_bfloat16* __restrict__ gate_ws) {
  __shared__ __attribute__((aligned(16))) short wbuf[16384];      // 32 KB stage
  __shared__ __attribute__((aligned(16))) float es_s[4][16][68];  // 17.4 KB
  const int tid = threadIdx.x;
  const int lane = tid & 63;
  const int wid = tid >> 6;
  const int g = lane >> 4;
  const int col = lane & 15;
  const int e0 = (blockIdx.x * 4 + wid) * 16;

  const short8v* lbh = (const short8v*)wbuf;
  const short8v* lbl = (const short8v*)(wbuf + 8192);
  auto stage = [&](const short* sh, const short* sl) {
    const short8v* gh = (const short8v*)sh;
    const short8v* gl = (const short8v*)sl;
    short8v* lh = (short8v*)wbuf;
    short8v* ll = (short8v*)(wbuf + 8192);
#pragma unroll
    for (int i = 0; i < 4; ++i) {
      lh[tid + i * 256] = gh[tid + i * 256];
      ll[tid + i * 256] = gl[tid + i * 256];
    }
  };

  // wave's 32 edge indices: lanes 0..15 = src, 16..31 = dst
  int l16 = lane & 15;
  int ecl16 = (e0 + l16 < NE) ? e0 + l16 : NE - 1;
  int idx_v = 0;
  if (lane < 32) idx_v = ei[(lane < 16 ? 0 : NE) + ecl16];

  int ecol = e0 + col; if (ecol >= NE) ecol = NE - 1;
  const float d = dist[ecol];

  // ---- A3 frags: raw 16B loads from packed xc (issued early) ----
  const short* ph = xch + (size_t)ecol * 128 + 8 * g;
  const short* pl = xcl + (size_t)ecol * 128 + 8 * g;
  short8v a3h[4], a3l[4];
#pragma unroll
  for (int kf = 0; kf < 4; ++kf) {
    a3h[kf] = *(const short8v*)(ph + kf * 32);
    a3l[kf] = *(const short8v*)(pl + kf * 32);
  }

  stage(Wp1h, Wp1l);

  // ---- rbf A-frags (computed while stage lands) ----
  short8v a1h[4], a1l[4];
#pragma unroll
  for (int kf = 0; kf < 4; ++kf) {
#pragma unroll
    for (int j = 0; j < 8; ++j) {
      int k = kf * 32 + 8 * g + j;
      float t = d - (float)k * (1.0f / 127.0f);
      float v = __expf(-8192.0f * t * t);
      short h, lo; f32_hilo(v, h, lo);
      a1h[kf][j] = h; a1l[kf][j] = lo;
    }
  }
  __syncthreads();

  const float4v z4 = {0.0f, 0.0f, 0.0f, 0.0f};

  // ---- GEMM1: es_raw(16x64) = rbf(16x128) @ W_rbf [B from LDS] ----
  float4v acc1[4];
#pragma unroll
  for (int nt = 0; nt < 4; ++nt) {
    float4v a = z4;
#pragma unroll
    for (int kf = 0; kf < 4; ++kf) {
      short8v bh = lbh[(nt * 4 + kf) * 64 + lane];
      short8v bl = lbl[(nt * 4 + kf) * 64 + lane];
      a = MFMA16(a1h[kf], bh, a);
      a = MFMA16(a1h[kf], bl, a);
      a = MFMA16(a1l[kf], bh, a);
    }
    acc1[nt] = a;
  }

  // ---- bias + silu -> es rows (per-wave LDS tile) ----
  int dn_r[4];
#pragma unroll
  for (int r = 0; r < 4; ++r) {
    int sn = __shfl(idx_v, 4 * g + r);
    dn_r[r] = __shfl(idx_v, 16 + 4 * g + r);
    int zs = zn[sn], zd = zn[dn_r[r]];
#pragma unroll
    for (int nt = 0; nt < 4; ++nt) {
      float b = aemb[zs * 64 + nt * 16 + col] + aemb[zd * 64 + nt * 16 + col];
      es_s[wid][4 * g + r][nt * 16 + col] = silu_f(acc1[nt][r] + b);
    }
  }
  __syncthreads();
  stage(Wp2h, Wp2l);

  // ---- GEMM2 A-frags from es rows (before the stage-barrier is fine:
  //      es_s region is disjoint from wbuf) ----
  short8v a2h[2], a2l[2];
#pragma unroll
  for (int kf = 0; kf < 2; ++kf) {
    const float* p = &es_s[wid][col][kf * 32 + 8 * g];
    float4v v0 = *(const float4v*)p;
    float4v v1 = *(const float4v*)(p + 4);
#pragma unroll
    for (int j = 0; j < 4; ++j) {
      short h, lo;
      f32_hilo(v0[j], h, lo); a2h[kf][j] = h;     a2l[kf][j] = lo;
      f32_hilo(v1[j], h, lo); a2h[kf][4 + j] = h; a2l[kf][4 + j] = lo;
    }
  }
  __syncthreads();

  // ---- GEMM2: gate = silu(es @ W_gate), store bf16 [B from LDS] ----
  float gate_r[8][4];
#pragma unroll
  for (int nt = 0; nt < 8; ++nt) {
    float4v a = z4;
#pragma unroll
    for (int kf = 0; kf < 2; ++kf) {
      short8v bh = lbh[(nt * 2 + kf) * 64 + lane];
      short8v bl = lbl[(nt * 2 + kf) * 64 + lane];
      a = MFMA16(a2h[kf], bh, a);
      a = MFMA16(a2h[kf], bl, a);
      a = MFMA16(a2l[kf], bh, a);
    }
#pragma unroll
    for (int r = 0; r < 4; ++r) {
      float gv = silu_f(a[r]);
      gate_r[nt][r] = gv;
      int er = e0 + 4 * g + r;
      if (er < NE)
        gate_ws[(size_t)er * 128 + nt * 16 + col] = __float2bfloat16(gv);
    }
  }
  __syncthreads();

  // ---- GEMM3 in two nt-halves (Wp3 is 64KB; stage 32KB at a time) ----
#pragma unroll
  for (int half = 0; half < 2; ++half) {
    stage(Wp3h + half * 8192, Wp3l + half * 8192);
    __syncthreads();
#pragma unroll
    for (int ntl = 0; ntl < 4; ++ntl) {
      int nt = half * 4 + ntl;
      float4v a = z4;
#pragma unroll
      for (int kf = 0; kf < 4; ++kf) {
        short8v bh = lbh[(ntl * 4 + kf) * 64 + lane];
        short8v bl = lbl[(ntl * 4 + kf) * 64 + lane];
        a = MFMA16(a3h[kf], bh, a);
        a = MFMA16(a3h[kf], bl, a);
        a = MFMA16(a3l[kf], bh, a);
      }
      float al = alpha[nt * 16 + col];
#pragma unroll
      for (int r = 0; r < 4; ++r) {
        float v = a[r] * gate_r[nt][r];
        v = v > 0.0f ? v : 0.2f * v;
        v *= al;
#pragma unroll
        for (int off = 1; off < 16; off <<= 1) v += __shfl_xor(v, off);
        int er = e0 + 4 * g + r;
        if (col == 0 && er < NE) {
          logits[(size_t)er * 8 + nt] = v;
          atomicMax(&m_enc[dn_r[r] * 8 + nt], enc_f(v));
        }
      }
    }
    __syncthreads();
  }
}

// ---------------- pass2: den[n,h] += exp(logit - m[n,h])  [unchanged]
__global__ void pass2_kernel(const float* __restrict__ logits,
                             const int* __restrict__ ei,
                             const unsigned int* __restrict__ m_enc,
                             float* __restrict__ den) {
  int i = blockIdx.x * blockDim.x + threadIdx.x;
  if (i >= NE * 8) return;
  int e = i >> 3, h = i & 7;
  int dn = ei[NE + e];
  float mm = dec_f(m_enc[dn * 8 + h]);
  atomicAdd(&den[dn * 8 + h], __expf(logits[i] - mm));
}

// ---------------- pass3 (fused, M=16): attn -> u -> t (MFMA) -> forces.
// [unchanged from r8]
__global__ __launch_bounds__(256, 3) void pass3_kernel(
    const int* __restrict__ ei, const float* __restrict__ logits,
    const unsigned int* __restrict__ m_enc, const float* __restrict__ den,
    const __hip_bfloat16* __restrict__ gate_ws, const float* __restrict__ Q,
    const short* __restrict__ Wp4h, const short* __restrict__ Wp4l,
    const short* __restrict__ Gb, float* __restrict__ out) {
  __shared__ __attribute__((aligned(16))) float attn_s[4][16][8];
  __shared__ __attribute__((aligned(16))) float x_s[4][16][132];  // u, then t
  const int tid = threadIdx.x;
  const int lane = tid & 63;
  const int wid = tid >> 6;
  const int g = lane >> 4;
  const int col = lane & 15;
  const int e0 = (blockIdx.x * 4 + wid) * 16;

  // ---- phase A: attn for 16 edges x 8 heads ----
#pragma unroll
  for (int half = 0; half < 2; ++half) {
    int i = half * 64 + lane;
    int e = i >> 3, h = i & 7;
    int ec = e0 + e; if (ec >= NE) ec = NE - 1;
    int dn = ei[NE + ec];
    float l = logits[(size_t)ec * 8 + h];
    float mm = dec_f(m_enc[dn * 8 + h]);
    float dv = den[dn * 8 + h];
    attn_s[wid][e][h] = __expf(l - mm) / (dv + 1e-9f);
  }

  // ---- phase B: u[e, m] for m = 2*lane, 2*lane+1 (paired bf16 gate load) ----
  float q0[8], q1[8];
#pragma unroll
  for (int h = 0; h < 8; ++h) {
    q0[h] = Q[(2 * lane) * 8 + h];
    q1[h] = Q[(2 * lane + 1) * 8 + h];
  }
#pragma unroll 4
  for (int e = 0; e < 16; ++e) {
    int ec = e0 + e; if (ec >= NE) ec = NE - 1;
    float4v a0 = *(const float4v*)&attn_s[wid][e][0];
    float4v a1 = *(const float4v*)&attn_s[wid][e][4];
    float wv0 = 0.0f, wv1 = 0.0f;
#pragma unroll
    for (int h = 0; h < 4; ++h) {
      wv0 += q0[h] * a0[h] + q0[4 + h] * a1[h];
      wv1 += q1[h] * a0[h] + q1[4 + h] * a1[h];
    }
    unsigned int gp = *(const unsigned int*)(gate_ws + (size_t)ec * 128 + 2 * lane);
    float gg0 = __uint_as_float((gp & 0xffffu) << 16);
    float gg1 = __uint_as_float((gp & 0xffff0000u));
    float2 uu; uu.x = gg0 * wv0; uu.y = gg1 * wv1;
    *(float2*)&x_s[wid][e][2 * lane] = uu;
  }

  // ---- phase C: A-frags from u, T = U @ Wp4 (96 MFMA), t -> x_s ----
  short8v ah[4], al[4];
#pragma unroll
  for (int kf = 0; kf < 4; ++kf) {
    const float* p = &x_s[wid][col][kf * 32 + 8 * g];
    float4v v0 = *(const float4v*)p;
    float4v v1 = *(const float4v*)(p + 4);
#pragma unroll
    for (int j = 0; j < 4; ++j) {
      short h, lo;
      f32_hilo(v0[j], h, lo); ah[kf][j] = h;     al[kf][j] = lo;
      f32_hilo(v1[j], h, lo); ah[kf][4 + j] = h; al[kf][4 + j] = lo;
    }
  }
  const float4v z4 = {0.0f, 0.0f, 0.0f, 0.0f};
#pragma unroll
  for (int nt = 0; nt < 8; ++nt) {
    float4v a = z4;
#pragma unroll
    for (int kf = 0; kf < 4; ++kf) {
      short8v bh = *(const short8v*)(Wp4h + ((nt * 4 + kf) * 64 + lane) * 8);
      short8v bl = *(const short8v*)(Wp4l + ((nt * 4 + kf) * 64 + lane) * 8);
      a = MFMA16(ah[kf], bh, a);
      a = MFMA16(ah[kf], bl, a);
      a = MFMA16(al[kf], bh, a);
    }
#pragma unroll
    for (int r = 0; r < 4; ++r)
      x_s[wid][4 * g + r][nt * 16 + col] = a[r];
  }

  // ---- phase D: forces from Gb (streaming) ; 4 edges parallel, 16 lanes each ----
  const int cg = col * 4;  // 4 channels per lane
#pragma unroll
  for (int it = 0; it < 4; ++it) {
    int e = it * 4 + g;
    int eu = e0 + e;
    bool valid = eu < NE;
    int ec = valid ? eu : NE - 1;
    int de = ei[NE + ec];
    float4v t0 = *(const float4v*)&x_s[wid][e][cg];
    float4v t1 = *(const float4v*)&x_s[wid][e][64 + cg];
    const short* gp = Gb + (size_t)ec * 384 + cg;
    float p[3];
#pragma unroll
    for (int i = 0; i < 3; ++i) {
      short4v gs = *(const short4v*)(gp + i * 64);
      short4v gt = *(const short4v*)(gp + (3 + i) * 64);
      p[i] = b2f(gs[0]) * t0[0] + b2f(gs[1]) * t0[1] + b2f(gs[2]) * t0[2] + b2f(gs[3]) * t0[3] +
             b2f(gt[0]) * t1[0] + b2f(gt[1]) * t1[1] + b2f(gt[2]) * t1[2] + b2f(gt[3]) * t1[3];
    }
#pragma unroll
    for (int i = 0; i < 3; ++i)
#pragma unroll
      for (int off = 1; off < 16; off <<= 1) p[i] += __shfl_xor(p[i], off);
    float pv = (col == 1) ? p[0] : ((col == 2) ? p[1] : p[2]);
    if (valid && col >= 1 && col <= 3)
      atomicAdd(&out[de * 3 + (col - 1)], pv);
  }
}

extern "C" void kernel_launch(void* const* d_in, const int* in_sizes, int n_in,
                              void* d_out, int out_size, void* d_ws, size_t ws_size,
                              hipStream_t stream) {
  const float* nb = (const float*)d_in[0];
  const int* zn = (const int*)d_in[1];
  const float* dist = (const float*)d_in[2];
  const int* ei = (const int*)d_in[3];
  const float* wig = (const float*)d_in[4];
  const float* aemb = (const float*)d_in[5];
  const float* W_rbf = (const float*)d_in[6];
  const float* W_gate = (const float*)d_in[7];
  const float* W_msg = (const float*)d_in[8];
  const float* alpha = (const float*)d_in[9];
  const float* W_val = (const float*)d_in[10];
  const float* W_out = (const float*)d_in[11];
  float* out = (float*)d_out;

  // workspace layout (~158 MB)
  char* p = (char*)d_ws;
  float* Q = (float*)p;                   p += 1024 * 4;
  unsigned int* m_enc = (unsigned int*)p; p += (size_t)NN * 8 * 4;
  float* den = (float*)p;                 p += (size_t)NN * 8 * 4;
  float* logits = (float*)p;              p += (size_t)NE * 8 * 4;
  __hip_bfloat16* gate_ws = (__hip_bfloat16*)p; p += (size_t)NE * 128 * 2;
  short* Wp1h = (short*)p; p += 8192 * 2;
  short* Wp1l = (short*)p; p += 8192 * 2;
  short* Wp2h = (short*)p; p += 8192 * 2;
  short* Wp2l = (short*)p; p += 8192 * 2;
  short* Wp3h = (short*)p; p += 16384 * 2;
  short* Wp3l = (short*)p; p += 16384 * 2;
  short* Wp4h = (short*)p; p += 16384 * 2;
  short* Wp4l = (short*)p; p += 16384 * 2;
  short* xch = (short*)p;                 p += (size_t)NE * 128 * 2;
  short* xcl = (short*)p;                 p += (size_t)NE * 128 * 2;
  short* Gb = (short*)p;                  p += (size_t)NE * 384 * 2;

  hipMemsetAsync(d_out, 0, (size_t)NN * 3 * 4, stream);
  hipMemsetAsync(m_enc, 0, (size_t)NN * 8 * 4, stream);
  hipMemsetAsync(den, 0, (size_t)NN * 8 * 4, stream);

  prep_kernel<<<192, 256, 0, stream>>>(W_msg, W_val, W_out, W_rbf, W_gate, Q,
                                       Wp1h, Wp1l, Wp2h, Wp2l, Wp3h, Wp3l, Wp4h, Wp4l);
  gather1_kernel<<<NE / 8, 256, 0, stream>>>(nb, ei, wig, xch, xcl, Gb);
  pass1_kernel<<<(NE + 63) / 64, 256, 0, stream>>>(zn, dist, ei, aemb, alpha,
                                                   xch, xcl,
                                                   Wp1h, Wp1l, Wp2h, Wp2l, Wp3h, Wp3l,
                                                   logits, m_enc, gate_ws);
  pass2_kernel<<<(NE * 8 + 255) / 256, 256, 0, stream>>>(logits, ei, m_enc, den);
  pass3_kernel<<<(NE + 63) / 64, 256, 0, stream>>>(ei, logits, m_enc, den,
                                                   gate_ws, Q, Wp4h, Wp4l, Gb, out);
}